// Round 2
// baseline (590.824 us; speedup 1.0000x reference)
//
#include <hip/hip_runtime.h>
#include <stdint.h>

#define BB 32
#define CC 512
#define HW 4096     // 64*64
#define HID 32      // C / 16

// ---------------------------------------------------------------------------
// Kernel 1: global average pool over H*W per (b,c).
// One block per (b,c); 256 threads; 4 x float4 loads per thread (16 KiB/plane).
// ---------------------------------------------------------------------------
__global__ __launch_bounds__(256) void se_pool(const float* __restrict__ x,
                                               float* __restrict__ v) {
    const int bc = blockIdx.x;                    // 0 .. B*C-1
    const float4* __restrict__ p4 = (const float4*)(x + (size_t)bc * HW);
    const int t = threadIdx.x;

    float s = 0.f;
#pragma unroll
    for (int it = 0; it < 4; ++it) {
        float4 d = p4[it * 256 + t];
        s += d.x + d.y + d.z + d.w;
    }
    // wave-64 shuffle reduction
#pragma unroll
    for (int off = 32; off > 0; off >>= 1) s += __shfl_down(s, off, 64);

    __shared__ float ws[4];
    const int lane = t & 63, wid = t >> 6;
    if (lane == 0) ws[wid] = s;
    __syncthreads();
    if (t == 0) {
        float tot = ws[0] + ws[1] + ws[2] + ws[3];
        v[bc] = tot * (1.0f / (float)HW);
    }
}

// ---------------------------------------------------------------------------
// Kernel 2: tiny MLP gate.  h = relu(v @ w1^T)  [32x32];  g = sigmoid(h @ w2^T)
// Single block, 1024 threads. v: [B][C] fp32, w1: [HID][C] fp32, w2: [C][HID] fp32.
// ---------------------------------------------------------------------------
__global__ __launch_bounds__(1024) void se_mlp(const float* __restrict__ v,
                                               const float* __restrict__ w1,
                                               const float* __restrict__ w2,
                                               float* __restrict__ g) {
    __shared__ float vs[BB * CC];       // 64 KiB
    __shared__ float h[BB * HID];       // 4 KiB
    const int t = threadIdx.x;

    for (int i = t; i < BB * CC; i += 1024) vs[i] = v[i];
    __syncthreads();

    // h[b][j], one per thread (exactly 1024 entries)
    {
        const int b = t >> 5, j = t & 31;
        const float* __restrict__ wr = w1 + j * CC;
        const float* __restrict__ vr = vs + b * CC;
        float s = 0.f;
        for (int c = 0; c < CC; ++c) s += vr[c] * wr[c];
        h[b * HID + j] = s > 0.f ? s : 0.f;
    }
    __syncthreads();

    // g[b][c], 16 per thread
    for (int e = t; e < BB * CC; e += 1024) {
        const int b = e >> 9, c = e & (CC - 1);
        const float* __restrict__ wr = w2 + c * HID;
        const float* __restrict__ hr = h + b * HID;
        float s = 0.f;
#pragma unroll
        for (int j = 0; j < HID; ++j) s += hr[j] * wr[j];
        g[e] = 1.0f / (1.0f + __expf(-s));
    }
}

// ---------------------------------------------------------------------------
// Kernel 3: out = x * g[b,c] broadcast. One block per (b,c).
// ---------------------------------------------------------------------------
__global__ __launch_bounds__(256) void se_scale(const float* __restrict__ x,
                                                const float* __restrict__ g,
                                                float* __restrict__ out) {
    const int bc = blockIdx.x;
    const float gate = g[bc];
    const float4* __restrict__ xp = (const float4*)(x + (size_t)bc * HW);
    float4* __restrict__ op = (float4*)(out + (size_t)bc * HW);
    const int t = threadIdx.x;

#pragma unroll
    for (int it = 0; it < 4; ++it) {
        float4 d = xp[it * 256 + t];
        d.x *= gate; d.y *= gate; d.z *= gate; d.w *= gate;
        op[it * 256 + t] = d;
    }
}

extern "C" void kernel_launch(void* const* d_in, const int* in_sizes, int n_in,
                              void* d_out, int out_size, void* d_ws, size_t ws_size,
                              hipStream_t stream) {
    const float* x  = (const float*)d_in[0];  // [B][C][H][W] fp32
    const float* w1 = (const float*)d_in[1];  // [HID][C] fp32
    const float* w2 = (const float*)d_in[2];  // [C][HID] fp32
    float* out = (float*)d_out;               // [B][C][H][W] fp32

    float* v = (float*)d_ws;          // B*C fp32  (64 KiB)
    float* g = v + BB * CC;           // B*C fp32  (64 KiB)

    se_pool <<<BB * CC, 256, 0, stream>>>(x, v);
    se_mlp  <<<1, 1024, 0, stream>>>(v, w1, w2, g);
    se_scale<<<BB * CC, 256, 0, stream>>>(x, g, out);
}